// Round 5
// baseline (2483.547 us; speedup 1.0000x reference)
//
#include <hip/hip_runtime.h>
#include <hip/hip_bf16.h>
#include <stdint.h>

#define D_MODEL 1024
#define VOCAB 50257
#define VP 51200          // padded vocab = NTILES * 256
#define ROWS 4096
#define RB 64             // rows (q) per block
#define VS 4              // vocab splits
#define VH (VP / VS)      // 12800
#define VT 256            // vocab tile per iter
#define ITERS (VH / VT)   // 50
#define NTILES (VS * ITERS) // 200
#define LN_EPS 1e-5f

typedef short s16x4 __attribute__((ext_vector_type(4)));
typedef short s16x8 __attribute__((ext_vector_type(8)));
typedef float f32x4 __attribute__((ext_vector_type(4)));
typedef float f32x16 __attribute__((ext_vector_type(16)));

__device__ __forceinline__ unsigned short f2bf(float f) {
  union { __hip_bfloat16 h; unsigned short u; } cv;
  cv.h = __float2bfloat16(f);
  return cv.u;
}
__device__ __forceinline__ float bf2f(unsigned short u) {
  union { float f; unsigned int i; } c;
  c.i = ((unsigned int)u) << 16;
  return c.f;
}

// ---- pack W [VOCAB][1024] fp32 -> frag-stream bf16 ----
// chunk cid = tile*32768 + s*4096 + ks*64 + l ; 16B chunks
// lane l of frag (tile,s,ks): v = tile*256 + s*32 + (l&31), k = ks*16 + (l>>5)*8
__global__ __launch_bounds__(256) void k_pack_w(const float* __restrict__ wsrc,
                                                unsigned short* __restrict__ wp) {
  const int cid = blockIdx.x * 256 + threadIdx.x;
  const int l = cid & 63;
  const int ks = (cid >> 6) & 63;
  const int s = (cid >> 12) & 7;
  const int tile = cid >> 15;
  const int v = tile * 256 + s * 32 + (l & 31);
  const int k = ks * 16 + (l >> 5) * 8;
  s16x8 o;
  if (v < VOCAB) {
    const f32x4* p = reinterpret_cast<const f32x4*>(wsrc + (size_t)v * D_MODEL + k);
    f32x4 a = p[0], b = p[1];
    o[0]=f2bf(a[0]); o[1]=f2bf(a[1]); o[2]=f2bf(a[2]); o[3]=f2bf(a[3]);
    o[4]=f2bf(b[0]); o[5]=f2bf(b[1]); o[6]=f2bf(b[2]); o[7]=f2bf(b[3]);
  } else {
    #pragma unroll
    for (int i = 0; i < 8; ++i) o[i] = 0;
  }
  reinterpret_cast<s16x8*>(wp)[cid] = o;
}

// ---- pack emb [VOCAB][1024] fp32 -> transposed frag-stream bf16 ----
// chunk cid = tile*32768 + w*4096 + ks2*256 + dt*64 + l  (w:8, ks2:16, dt:4)
// lane l: d = (dt*8+w)*32 + (l&31), v = tile*256 + ks2*16 + (l>>5)*8 + j
__global__ __launch_bounds__(256) void k_pack_e(const float* __restrict__ emb,
                                                unsigned short* __restrict__ ep) {
  __shared__ unsigned short tileS[256][33];
  const int tile = blockIdx.x;       // [0,200)
  const int dblk = blockIdx.y;       // [0,32): d-slice [dblk*32,+32); w=dblk&7, dt=dblk>>3
  const int w = dblk & 7, dt = dblk >> 3;
  const int t = threadIdx.x;
  {
    const int v = tile * 256 + t;
    if (v < VOCAB) {
      const f32x4* src = reinterpret_cast<const f32x4*>(emb + (size_t)v * D_MODEL + dblk * 32);
      #pragma unroll
      for (int i = 0; i < 8; ++i) {
        f32x4 a = src[i];
        #pragma unroll
        for (int j = 0; j < 4; ++j) tileS[t][i * 4 + j] = f2bf(a[j]);
      }
    } else {
      #pragma unroll
      for (int i = 0; i < 32; ++i) tileS[t][i] = 0;
    }
  }
  __syncthreads();
  #pragma unroll
  for (int i = 0; i < 4; ++i) {
    const int c = t + i * 256;
    const int l = c & 63;
    const int ks2 = c >> 6;           // [0,16)
    const int dloc = l & 31;
    s16x8 o;
    #pragma unroll
    for (int j = 0; j < 8; ++j) o[j] = tileS[ks2 * 16 + (l >> 5) * 8 + j][dloc];
    const size_t cid = (size_t)tile * 32768 + (size_t)w * 4096 + (size_t)ks2 * 256
                     + (size_t)dt * 64 + l;
    reinterpret_cast<s16x8*>(ep)[cid] = o;
  }
}

// ---- pad+convert bias to bf16 [VP] ----
__global__ __launch_bounds__(256) void k_pack_bias(const float* __restrict__ b,
                                                   unsigned short* __restrict__ bp) {
  const int v = blockIdx.x * 256 + threadIdx.x;
  bp[v] = f2bf(v < VOCAB ? b[v] : 0.f);
}

// ---- main fused kernel: 256 blocks (1/CU), 8 waves ----
// phase 1: wave w owns v-stripe w (32 v), computes S for BOTH q-tiles (W frag -> 2 MFMA)
// phase 2: wave w owns d-set {(dt*8+w)*32} (128 d), both q-tiles (E frag -> 2 MFMA)
__global__ __launch_bounds__(512, 2)
void k_main(const float* __restrict__ enc, const unsigned short* __restrict__ biasb,
            const unsigned short* __restrict__ Wp, const unsigned short* __restrict__ Ep,
            float* __restrict__ o_part, float* __restrict__ den_part) {
  __shared__ unsigned short Qf[65536];   // 128 KB frag-ordered Q
  __shared__ unsigned short Pl[16384];   // 32 KB: P[64 q][256 v] bf16, XOR-swizzled

  const int bx = blockIdx.x;
  const int xcd = bx & 7;
  const int vs = xcd & 3;
  const int rb = (xcd >> 2) * 32 + (bx >> 3);   // [0,64)
  const int row0 = rb * RB;
  const int tid = threadIdx.x;
  const int w = tid >> 6;          // 0..7
  const int l = tid & 63;
  const int l31 = l & 31;
  const int lh = l >> 5;

  // ---- stage Q frag-ordered: frag (qt,ks) lane ((kc&1)<<5)|(q&31) ----
  for (int c = tid; c < RB * 128; c += 512) {
    const int qq = c >> 7;
    const int kc = c & 127;
    const f32x4* src = reinterpret_cast<const f32x4*>(enc + (size_t)(row0 + qq) * D_MODEL + kc * 8);
    f32x4 a = src[0], b = src[1];
    s16x8 o;
    o[0]=f2bf(a[0]); o[1]=f2bf(a[1]); o[2]=f2bf(a[2]); o[3]=f2bf(a[3]);
    o[4]=f2bf(b[0]); o[5]=f2bf(b[1]); o[6]=f2bf(b[2]); o[7]=f2bf(b[3]);
    const int qtt = qq >> 5, ks = kc >> 1, lane = ((kc & 1) << 5) | (qq & 31);
    reinterpret_cast<s16x8*>(Qf)[(qtt * 64 + ks) * 64 + lane] = o;
  }
  __syncthreads();

  const s16x8* Qv = reinterpret_cast<const s16x8*>(Qf);
  char* PlB = reinterpret_cast<char*>(Pl);
  const uint32_t swz = (uint32_t)(l31 & 15) << 4;

  float den0 = 0.f, den1 = 0.f;
  f32x16 Oacc[4][2];
  #pragma unroll
  for (int dt = 0; dt < 4; ++dt)
    #pragma unroll
    for (int qt = 0; qt < 2; ++qt)
      #pragma unroll
      for (int i = 0; i < 16; ++i) Oacc[dt][qt][i] = 0.f;

  for (int it = 0; it < ITERS; ++it) {
    const int tile = vs * ITERS + it;

    // bias for this tile/stripe, loaded early (bf16)
    const unsigned short* bb = biasb + tile * 256 + w * 32 + 4 * lh;
    const s16x4 b0 = *reinterpret_cast<const s16x4*>(bb);
    const s16x4 b1 = *reinterpret_cast<const s16x4*>(bb + 8);
    const s16x4 b2 = *reinterpret_cast<const s16x4*>(bb + 16);
    const s16x4 b3 = *reinterpret_cast<const s16x4*>(bb + 24);

    // ---- phase 1: S = W.Q^T with ring-4 W prefetch ----
    f32x16 S0, S1;
    #pragma unroll
    for (int i = 0; i < 16; ++i) { S0[i] = 0.f; S1[i] = 0.f; }
    const s16x8* wv = reinterpret_cast<const s16x8*>(Wp) + (size_t)tile * 32768 + w * 4096 + l;
    s16x8 wbuf[4];
    #pragma unroll
    for (int i = 0; i < 4; ++i) wbuf[i] = wv[(size_t)i * 64];
    #pragma unroll
    for (int ks = 0; ks < 64; ++ks) {
      const s16x8 wf = wbuf[ks & 3];
      if (ks + 4 < 64) wbuf[ks & 3] = wv[(size_t)(ks + 4) * 64];
      const s16x8 q0 = Qv[(size_t)(0 * 64 + ks) * 64 + l];
      const s16x8 q1 = Qv[(size_t)(1 * 64 + ks) * 64 + l];
      S0 = __builtin_amdgcn_mfma_f32_32x32x16_bf16(wf, q0, S0, 0, 0, 0);
      S1 = __builtin_amdgcn_mfma_f32_32x32x16_bf16(wf, q1, S1, 0, 0, 0);
    }
    __syncthreads();  // barrier A: all phase-2 reads of Pl(it-1) done

    // issue first E-group now: latency hides under exp + barrier B (T14)
    const s16x8* ev = reinterpret_cast<const s16x8*>(Ep) + (size_t)tile * 32768 + w * 4096 + l;
    s16x8 ebuf[2][4];
    #pragma unroll
    for (int dt = 0; dt < 4; ++dt) ebuf[0][dt] = ev[(size_t)dt * 64];

    // ---- exp + bias + P write + denom ----
    {
      const int vbase = tile * 256 + w * 32 + 4 * lh;
      const uint32_t vb2base = (uint32_t)(w * 32 + 4 * lh) * 2u;
      #pragma unroll
      for (int m = 0; m < 4; ++m) {
        const s16x4 bm = (m == 0) ? b0 : (m == 1) ? b1 : (m == 2) ? b2 : b3;
        s16x4 pk0, pk1;
        #pragma unroll
        for (int r = 0; r < 4; ++r) {
          const float bvr = bf2f((unsigned short)bm[r]);
          float e0 = __expf(S0[4 * m + r] + bvr);
          float e1 = __expf(S1[4 * m + r] + bvr);
          if (vbase + 8 * m + r >= VOCAB) { e0 = 0.f; e1 = 0.f; }
          den0 += e0; den1 += e1;
          pk0[r] = f2bf(e0); pk1[r] = f2bf(e1);
        }
        const uint32_t vb2 = vb2base + (uint32_t)(8 * m) * 2u;
        const uint32_t byte0 = (uint32_t)l31 * 512u + (vb2 ^ swz);
        const uint32_t byte1 = (uint32_t)(32 + l31) * 512u + (vb2 ^ swz);
        *reinterpret_cast<s16x4*>(PlB + byte0) = pk0;
        *reinterpret_cast<s16x4*>(PlB + byte1) = pk1;
      }
    }
    __syncthreads();  // barrier B: Pl ready

    // ---- phase 2: O += embT.P^T with ring-2 E prefetch ----
    #pragma unroll
    for (int ks2 = 0; ks2 < 16; ++ks2) {
      if (ks2 + 1 < 16) {
        #pragma unroll
        for (int dt = 0; dt < 4; ++dt)
          ebuf[(ks2 + 1) & 1][dt] = ev[(size_t)(ks2 + 1) * 256 + dt * 64];
      }
      const uint32_t voff = (uint32_t)(ks2 * 32 + lh * 16);
      const s16x8 p0 = *reinterpret_cast<const s16x8*>(PlB + (uint32_t)l31 * 512u + (voff ^ swz));
      const s16x8 p1 = *reinterpret_cast<const s16x8*>(PlB + (uint32_t)(32 + l31) * 512u + (voff ^ swz));
      #pragma unroll
      for (int dt = 0; dt < 4; ++dt) {
        const s16x8 ef = ebuf[ks2 & 1][dt];
        Oacc[dt][0] = __builtin_amdgcn_mfma_f32_32x32x16_bf16(ef, p0, Oacc[dt][0], 0, 0, 0);
        Oacc[dt][1] = __builtin_amdgcn_mfma_f32_32x32x16_bf16(ef, p1, Oacc[dt][1], 0, 0, 0);
      }
    }
  }

  // ---- write O partials: row = row0 + qt*32 + l31, d = (dt*8+w)*32 + 4lh + 8m + r ----
  float* ob = o_part + ((size_t)vs * ROWS + row0) * D_MODEL;
  #pragma unroll
  for (int qt = 0; qt < 2; ++qt) {
    #pragma unroll
    for (int dt = 0; dt < 4; ++dt) {
      const f32x16& A = Oacc[dt][qt];
      const size_t rowoff = (size_t)(qt * 32 + l31) * D_MODEL;
      const int dbase = (dt * 8 + w) * 32 + 4 * lh;
      #pragma unroll
      for (int m = 0; m < 4; ++m) {
        f32x4 v4 = { A[4 * m], A[4 * m + 1], A[4 * m + 2], A[4 * m + 3] };
        *reinterpret_cast<f32x4*>(ob + rowoff + dbase + 8 * m) = v4;
      }
    }
  }

  // ---- denom reduce (reuse Pl after sync) ----
  __syncthreads();
  den0 += __shfl_xor(den0, 32);
  den1 += __shfl_xor(den1, 32);
  float* red = reinterpret_cast<float*>(Pl);
  if (l < 32) {
    red[(w * 2 + 0) * 32 + l31] = den0;
    red[(w * 2 + 1) * 32 + l31] = den1;
  }
  __syncthreads();
  if (tid < 64) {
    const int qtt = tid >> 5, col = tid & 31;
    float s = 0.f;
    #pragma unroll
    for (int s2 = 0; s2 < 8; ++s2) s += red[(s2 * 2 + qtt) * 32 + col];
    den_part[(size_t)vs * ROWS + row0 + tid] = s;
  }
}

// ---- epilogue: combine partials, residual, LayerNorm ----
__global__ __launch_bounds__(256)
void k_ln(const float* __restrict__ enc, const float* __restrict__ o_part,
          const float* __restrict__ den_part, const float* __restrict__ gam,
          const float* __restrict__ bet, float* __restrict__ out) {
  __shared__ float r1[4], r2[4];
  const int row = blockIdx.x;
  const int t = threadIdx.x;
  const int d = t * 4;
  float den = 0.f;
  #pragma unroll
  for (int p = 0; p < VS; ++p) den += den_part[(size_t)p * ROWS + row];
  const float inv = 1.f / den;
  f32x4 acc = {0.f, 0.f, 0.f, 0.f};
  #pragma unroll
  for (int p = 0; p < VS; ++p) {
    const f32x4 a = *reinterpret_cast<const f32x4*>(o_part + ((size_t)p * ROWS + row) * D_MODEL + d);
    #pragma unroll
    for (int jj = 0; jj < 4; ++jj) acc[jj] += a[jj];
  }
  const f32x4 e = *reinterpret_cast<const f32x4*>(enc + (size_t)row * D_MODEL + d);
  f32x4 y;
  #pragma unroll
  for (int jj = 0; jj < 4; ++jj) y[jj] = e[jj] + acc[jj] * inv;
  float s1 = y[0] + y[1] + y[2] + y[3];
  float s2 = y[0]*y[0] + y[1]*y[1] + y[2]*y[2] + y[3]*y[3];
  #pragma unroll
  for (int off = 1; off < 64; off <<= 1) {
    s1 += __shfl_xor(s1, off);
    s2 += __shfl_xor(s2, off);
  }
  if ((t & 63) == 0) { r1[t >> 6] = s1; r2[t >> 6] = s2; }
  __syncthreads();
  const float S1 = r1[0] + r1[1] + r1[2] + r1[3];
  const float S2 = r2[0] + r2[1] + r2[2] + r2[3];
  const float mean = S1 * (1.f / D_MODEL);
  const float var = S2 * (1.f / D_MODEL) - mean * mean;
  const float rs = rsqrtf(var + LN_EPS);
  const f32x4 gv = *reinterpret_cast<const f32x4*>(gam + d);
  const f32x4 bv = *reinterpret_cast<const f32x4*>(bet + d);
  f32x4 o;
  #pragma unroll
  for (int jj = 0; jj < 4; ++jj) o[jj] = (y[jj] - mean) * rs * gv[jj] + bv[jj];
  *reinterpret_cast<f32x4*>(out + (size_t)row * D_MODEL + d) = o;
}

extern "C" void kernel_launch(void* const* d_in, const int* in_sizes, int n_in,
                              void* d_out, int out_size, void* d_ws, size_t ws_size,
                              hipStream_t stream) {
  const float* enc = (const float*)d_in[0];
  const float* pw  = (const float*)d_in[1];
  const float* pb  = (const float*)d_in[2];
  const float* emb = (const float*)d_in[3];
  const float* gam = (const float*)d_in[4];
  const float* bet = (const float*)d_in[5];
  float* out = (float*)d_out;

  size_t off = 0;
  unsigned short* Wp = (unsigned short*)((char*)d_ws + off); off += (size_t)NTILES * 32768 * 16;  // 104.86 MB
  unsigned short* Ep = (unsigned short*)((char*)d_ws + off); off += (size_t)NTILES * 32768 * 16;  // 104.86 MB
  unsigned short* biasb = (unsigned short*)((char*)d_ws + off); off += (size_t)VP * 2;
  float* o_part = (float*)((char*)d_ws + off); off += (size_t)VS * ROWS * D_MODEL * 4;            // 67.1 MB
  float* den_part = (float*)((char*)d_ws + off); off += (size_t)VS * ROWS * 4;

  if (off > ws_size) {
    // unambiguous sentinel: ws too small -> absmax ~3.4e38
    hipMemsetAsync(d_out, 0x7f, (size_t)out_size * 4, stream);
    return;
  }

  k_pack_w<<<NTILES * 32768 / 256, 256, 0, stream>>>(pw, Wp);
  k_pack_e<<<dim3(NTILES, 32), 256, 0, stream>>>(emb, Ep);
  k_pack_bias<<<VP / 256, 256, 0, stream>>>(pb, biasb);
  k_main<<<256, 512, 0, stream>>>(enc, biasb, Wp, Ep, o_part, den_part);
  k_ln<<<ROWS, 256, 0, stream>>>(enc, o_part, den_part, gam, bet, out);
}

// Round 6
// 1283.429 us; speedup vs baseline: 1.9351x; 1.9351x over previous
//
#include <hip/hip_runtime.h>
#include <hip/hip_bf16.h>
#include <stdint.h>

#define D_MODEL 1024
#define VOCAB 50257
#define VP 51200          // padded vocab
#define ROWS 4096
#define LN_EPS 1e-5f

// ---- fallback (fused) path params ----
#define RB 64
#define VS 4
#define VH (VP / VS)      // 12800
#define VT 256
#define ITERS (VH / VT)   // 50
#define NTILES (VS * ITERS) // 200

typedef short s16x4 __attribute__((ext_vector_type(4)));
typedef short s16x8 __attribute__((ext_vector_type(8)));
typedef float f32x4 __attribute__((ext_vector_type(4)));
typedef float f32x16 __attribute__((ext_vector_type(16)));

__device__ __forceinline__ unsigned short f2bf(float f) {
  union { __hip_bfloat16 h; unsigned short u; } cv;
  cv.h = __float2bfloat16(f);
  return cv.u;
}
__device__ __forceinline__ float bf2f(unsigned short u) {
  union { float f; unsigned int i; } c;
  c.i = ((unsigned int)u) << 16;
  return c.f;
}
__device__ __forceinline__ void gload_lds16(const void* g, void* l) {
  __builtin_amdgcn_global_load_lds(
      (const __attribute__((address_space(1))) unsigned int*)g,
      (__attribute__((address_space(3))) unsigned int*)l, 16, 0, 0);
}

// ============================================================================
// NEW PATH: split GEMMs, global_load_lds staged, m97-style 2-barrier K-loop
// ============================================================================

// ---- enc fp32 -> bf16 [4096][1024] ----
__global__ __launch_bounds__(256) void k_cast_enc(const float* __restrict__ src,
                                                  unsigned short* __restrict__ dst) {
  const size_t i0 = ((size_t)blockIdx.x * 256 + threadIdx.x) * 8;
  const f32x4* p = reinterpret_cast<const f32x4*>(src + i0);
  f32x4 a = p[0], b = p[1];
  s16x8 o;
  o[0]=f2bf(a[0]); o[1]=f2bf(a[1]); o[2]=f2bf(a[2]); o[3]=f2bf(a[3]);
  o[4]=f2bf(b[0]); o[5]=f2bf(b[1]); o[6]=f2bf(b[2]); o[7]=f2bf(b[3]);
  *reinterpret_cast<s16x8*>(dst + i0) = o;
}

// ---- W fp32 [VOCAB][1024] -> bf16 [VP][1024] zero-padded (same layout) ----
__global__ __launch_bounds__(256) void k_pack_wlin(const float* __restrict__ src,
                                                   unsigned short* __restrict__ dst) {
  const size_t i0 = ((size_t)blockIdx.x * 256 + threadIdx.x) * 8;
  const int v = (int)(i0 >> 10);
  s16x8 o;
  if (v < VOCAB) {
    const f32x4* p = reinterpret_cast<const f32x4*>(src + i0);
    f32x4 a = p[0], b = p[1];
    o[0]=f2bf(a[0]); o[1]=f2bf(a[1]); o[2]=f2bf(a[2]); o[3]=f2bf(a[3]);
    o[4]=f2bf(b[0]); o[5]=f2bf(b[1]); o[6]=f2bf(b[2]); o[7]=f2bf(b[3]);
  } else {
    #pragma unroll
    for (int i = 0; i < 8; ++i) o[i] = 0;
  }
  *reinterpret_cast<s16x8*>(dst + i0) = o;
}

// ---- emb [VOCAB][1024] fp32 -> ET bf16 [1024][VP] (transpose, zero-pad) ----
__global__ __launch_bounds__(256) void k_pack_et(const float* __restrict__ emb,
                                                 unsigned short* __restrict__ et) {
  __shared__ float tile[32][33];
  const int v0 = blockIdx.x * 32;
  const int d0 = blockIdx.y * 32;
  const int tx = threadIdx.x, ty = threadIdx.y;  // 32 x 8
  #pragma unroll
  for (int i = 0; i < 4; ++i) {
    const int v = v0 + ty + 8 * i;
    tile[ty + 8 * i][tx] = (v < VOCAB) ? emb[(size_t)v * D_MODEL + d0 + tx] : 0.f;
  }
  __syncthreads();
  #pragma unroll
  for (int i = 0; i < 4; ++i) {
    const int d = d0 + ty + 8 * i;
    et[(size_t)d * VP + v0 + tx] = f2bf(tile[tx][ty + 8 * i]);
  }
}

// ---- GEMM1: P = exp(enc.W^T + b)  [4096 x VP], K=1024 ----
// 128(q) x 256(v) tile, BK=64, 8 waves (2m x 4n), wave 64x64, 16 K-steps.
__global__ __launch_bounds__(512, 4)
void k_gemm1(const unsigned short* __restrict__ encb,
             const unsigned short* __restrict__ Wb,
             const float* __restrict__ bias,
             unsigned short* __restrict__ P,
             float* __restrict__ den) {
  __shared__ __align__(16) unsigned short As[128 * 64];  // 16 KB swizzled
  __shared__ __align__(16) unsigned short Bs[256 * 64];  // 32 KB swizzled

  const int bx = blockIdx.x;
  const int xcd = bx & 7, bi = bx >> 3;      // 800 per XCD-slot
  const int nt_ = xcd * 25 + bi % 25;        // v-tile 0..199 (contiguous per XCD)
  const int mt_ = bi / 25;                   // q-tile 0..31
  const int row0 = mt_ * 128;
  const int col0 = nt_ * 256;

  const int tid = threadIdx.x;
  const int w = tid >> 6, l = tid & 63;
  const int mw = w >> 2, nw = w & 3;
  const int r16 = l & 15, g = l >> 4;

  f32x4 acc[4][4];
  #pragma unroll
  for (int a = 0; a < 4; ++a)
    #pragma unroll
    for (int b = 0; b < 4; ++b) acc[a][b] = f32x4{0.f, 0.f, 0.f, 0.f};

  uint32_t arow[4], asw[4], brow[4], bsw[4];
  #pragma unroll
  for (int t = 0; t < 4; ++t) {
    const uint32_t ar = mw * 64 + t * 16 + r16;
    arow[t] = ar * 128; asw[t] = (ar & 7) << 4;
    const uint32_t br = nw * 64 + t * 16 + r16;
    brow[t] = br * 128; bsw[t] = (br & 7) << 4;
  }

  for (int kt = 0; kt < 16; ++kt) {
    __syncthreads();   // prev compute done before overwrite
    #pragma unroll
    for (int ii = 0; ii < 2; ++ii) {  // A: 1024 16B chunks
      const int c = tid + ii * 512;
      const int r = c >> 3, s2 = (c & 7) ^ (r & 7);
      gload_lds16(encb + (size_t)(row0 + r) * 1024 + kt * 64 + s2 * 8, &As[c * 8]);
    }
    #pragma unroll
    for (int ii = 0; ii < 4; ++ii) {  // B: 2048 chunks
      const int c = tid + ii * 512;
      const int r = c >> 3, s2 = (c & 7) ^ (r & 7);
      gload_lds16(Wb + (size_t)(col0 + r) * 1024 + kt * 64 + s2 * 8, &Bs[c * 8]);
    }
    __syncthreads();   // vmcnt(0) drain + barrier

    #pragma unroll
    for (int kk = 0; kk < 2; ++kk) {
      const uint32_t ksl = (uint32_t)((kk * 4 + g) << 4);
      s16x8 af[4], bf[4];
      #pragma unroll
      for (int t = 0; t < 4; ++t) {
        af[t] = *reinterpret_cast<const s16x8*>(
            reinterpret_cast<const char*>(As) + arow[t] + (ksl ^ asw[t]));
        bf[t] = *reinterpret_cast<const s16x8*>(
            reinterpret_cast<const char*>(Bs) + brow[t] + (ksl ^ bsw[t]));
      }
      #pragma unroll
      for (int a = 0; a < 4; ++a)
        #pragma unroll
        for (int b = 0; b < 4; ++b)
          acc[a][b] = __builtin_amdgcn_mfma_f32_16x16x32_bf16(af[a], bf[b], acc[a][b], 0, 0, 0);
    }
  }

  // epilogue: exp(S + bias), write P bf16, per-row denom atomics
  float biasv[4];
  #pragma unroll
  for (int b = 0; b < 4; ++b) {
    const int v = col0 + nw * 64 + b * 16 + r16;
    biasv[b] = (v < VOCAB) ? bias[v] : 0.f;
  }
  #pragma unroll
  for (int a = 0; a < 4; ++a) {
    #pragma unroll
    for (int j = 0; j < 4; ++j) {
      const int q = row0 + mw * 64 + a * 16 + g * 4 + j;
      float rsum = 0.f;
      #pragma unroll
      for (int b = 0; b < 4; ++b) {
        const int v = col0 + nw * 64 + b * 16 + r16;
        float e = (v < VOCAB) ? __expf(acc[a][b][j] + biasv[b]) : 0.f;
        rsum += e;
        P[(size_t)q * VP + v] = f2bf(e);
      }
      rsum += __shfl_xor(rsum, 1);
      rsum += __shfl_xor(rsum, 2);
      rsum += __shfl_xor(rsum, 4);
      rsum += __shfl_xor(rsum, 8);
      if (r16 == 0) atomicAdd(&den[(size_t)q * 8 + (nt_ & 7)], rsum);
    }
  }
}

// ---- GEMM2: opart[ks] = P.ET^T slice, K-split 8 over VP ----
// 256(q) x 128(d) tile, BK=64, 8 waves (4m x 2n), wave 64x64, 100 K-steps.
__global__ __launch_bounds__(512, 4)
void k_gemm2(const unsigned short* __restrict__ P,
             const unsigned short* __restrict__ ET,
             float* __restrict__ opart) {
  __shared__ __align__(16) unsigned short As[256 * 64];  // 32 KB P rows
  __shared__ __align__(16) unsigned short Bs[128 * 64];  // 16 KB ET rows

  const int bx = blockIdx.x;
  const int ks = bx & 7, bi = bx >> 3;       // XCD owns one K-split
  const int mt_ = bi & 15, nd = bi >> 4;     // q-tile 0..15, d-tile 0..7
  const int row0 = mt_ * 256, col0 = nd * 128;
  const int k0 = ks * (VP / 8);              // 6400

  const int tid = threadIdx.x;
  const int w = tid >> 6, l = tid & 63;
  const int mw = w >> 1, nw = w & 1;
  const int r16 = l & 15, g = l >> 4;

  f32x4 acc[4][4];
  #pragma unroll
  for (int a = 0; a < 4; ++a)
    #pragma unroll
    for (int b = 0; b < 4; ++b) acc[a][b] = f32x4{0.f, 0.f, 0.f, 0.f};

  uint32_t arow[4], asw[4], brow[4], bsw[4];
  #pragma unroll
  for (int t = 0; t < 4; ++t) {
    const uint32_t ar = mw * 64 + t * 16 + r16;
    arow[t] = ar * 128; asw[t] = (ar & 7) << 4;
    const uint32_t br = nw * 64 + t * 16 + r16;
    brow[t] = br * 128; bsw[t] = (br & 7) << 4;
  }

  for (int kt = 0; kt < 100; ++kt) {
    const int koff = k0 + kt * 64;
    __syncthreads();
    #pragma unroll
    for (int ii = 0; ii < 4; ++ii) {  // A: 2048 chunks
      const int c = tid + ii * 512;
      const int r = c >> 3, s2 = (c & 7) ^ (r & 7);
      gload_lds16(P + (size_t)(row0 + r) * VP + koff + s2 * 8, &As[c * 8]);
    }
    #pragma unroll
    for (int ii = 0; ii < 2; ++ii) {  // B: 1024 chunks
      const int c = tid + ii * 512;
      const int r = c >> 3, s2 = (c & 7) ^ (r & 7);
      gload_lds16(ET + (size_t)(col0 + r) * VP + koff + s2 * 8, &Bs[c * 8]);
    }
    __syncthreads();

    #pragma unroll
    for (int kk = 0; kk < 2; ++kk) {
      const uint32_t ksl = (uint32_t)((kk * 4 + g) << 4);
      s16x8 af[4], bf[4];
      #pragma unroll
      for (int t = 0; t < 4; ++t) {
        af[t] = *reinterpret_cast<const s16x8*>(
            reinterpret_cast<const char*>(As) + arow[t] + (ksl ^ asw[t]));
        bf[t] = *reinterpret_cast<const s16x8*>(
            reinterpret_cast<const char*>(Bs) + brow[t] + (ksl ^ bsw[t]));
      }
      #pragma unroll
      for (int a = 0; a < 4; ++a)
        #pragma unroll
        for (int b = 0; b < 4; ++b)
          acc[a][b] = __builtin_amdgcn_mfma_f32_16x16x32_bf16(af[a], bf[b], acc[a][b], 0, 0, 0);
    }
  }

  // epilogue: write f32 partial [ks][q][d]
  #pragma unroll
  for (int a = 0; a < 4; ++a) {
    #pragma unroll
    for (int j = 0; j < 4; ++j) {
      const int q = row0 + mw * 64 + a * 16 + g * 4 + j;
      float* orow = opart + ((size_t)ks * ROWS + q) * D_MODEL;
      #pragma unroll
      for (int b = 0; b < 4; ++b) {
        const int d = col0 + nw * 64 + b * 16 + r16;
        orow[d] = acc[a][b][j];
      }
    }
  }
}

// ---- LN epilogue (new path): combine 8 partials + den, residual, LayerNorm ----
__global__ __launch_bounds__(256)
void k_ln2(const float* __restrict__ enc, const float* __restrict__ opart,
           const float* __restrict__ den, const float* __restrict__ gam,
           const float* __restrict__ bet, float* __restrict__ out) {
  __shared__ float r1[4], r2[4];
  const int row = blockIdx.x;
  const int t = threadIdx.x;
  const int d = t * 4;
  float dn = 0.f;
  #pragma unroll
  for (int s = 0; s < 8; ++s) dn += den[(size_t)row * 8 + s];
  const float inv = 1.f / dn;
  f32x4 acc = {0.f, 0.f, 0.f, 0.f};
  #pragma unroll
  for (int ks = 0; ks < 8; ++ks) {
    const f32x4 a = *reinterpret_cast<const f32x4*>(opart + ((size_t)ks * ROWS + row) * D_MODEL + d);
    #pragma unroll
    for (int jj = 0; jj < 4; ++jj) acc[jj] += a[jj];
  }
  const f32x4 e = *reinterpret_cast<const f32x4*>(enc + (size_t)row * D_MODEL + d);
  f32x4 y;
  #pragma unroll
  for (int jj = 0; jj < 4; ++jj) y[jj] = e[jj] + acc[jj] * inv;
  float s1 = y[0] + y[1] + y[2] + y[3];
  float s2 = y[0]*y[0] + y[1]*y[1] + y[2]*y[2] + y[3]*y[3];
  #pragma unroll
  for (int off = 1; off < 64; off <<= 1) {
    s1 += __shfl_xor(s1, off);
    s2 += __shfl_xor(s2, off);
  }
  if ((t & 63) == 0) { r1[t >> 6] = s1; r2[t >> 6] = s2; }
  __syncthreads();
  const float S1 = r1[0] + r1[1] + r1[2] + r1[3];
  const float S2 = r2[0] + r2[1] + r2[2] + r2[3];
  const float mean = S1 * (1.f / D_MODEL);
  const float var = S2 * (1.f / D_MODEL) - mean * mean;
  const float rs = rsqrtf(var + LN_EPS);
  const f32x4 gv = *reinterpret_cast<const f32x4*>(gam + d);
  const f32x4 bv = *reinterpret_cast<const f32x4*>(bet + d);
  f32x4 o;
  #pragma unroll
  for (int jj = 0; jj < 4; ++jj) o[jj] = (y[jj] - mean) * rs * gv[jj] + bv[jj];
  *reinterpret_cast<f32x4*>(out + (size_t)row * D_MODEL + d) = o;
}

// ============================================================================
// FALLBACK PATH (R3, 1596 us): fused kernel set — used if ws_size too small
// ============================================================================

__global__ __launch_bounds__(256) void k_pack_w(const float* __restrict__ wsrc,
                                                unsigned short* __restrict__ wp) {
  const int cid = blockIdx.x * 256 + threadIdx.x;
  const int l = cid & 63;
  const int ks = (cid >> 6) & 63;
  const int s = (cid >> 12) & 7;
  const int tile = cid >> 15;
  const int v = tile * 256 + s * 32 + (l & 31);
  const int k = ks * 16 + (l >> 5) * 8;
  s16x8 o;
  if (v < VOCAB) {
    const f32x4* p = reinterpret_cast<const f32x4*>(wsrc + (size_t)v * D_MODEL + k);
    f32x4 a = p[0], b = p[1];
    o[0]=f2bf(a[0]); o[1]=f2bf(a[1]); o[2]=f2bf(a[2]); o[3]=f2bf(a[3]);
    o[4]=f2bf(b[0]); o[5]=f2bf(b[1]); o[6]=f2bf(b[2]); o[7]=f2bf(b[3]);
  } else {
    #pragma unroll
    for (int i = 0; i < 8; ++i) o[i] = 0;
  }
  reinterpret_cast<s16x8*>(wp)[cid] = o;
}

__global__ __launch_bounds__(256) void k_pack_e(const float* __restrict__ emb,
                                                unsigned short* __restrict__ ep) {
  __shared__ unsigned short tileS[256][33];
  const int tile = blockIdx.x;
  const int dblk = blockIdx.y;
  const int w = dblk & 7, dt = dblk >> 3;
  const int t = threadIdx.x;
  {
    const int v = tile * 256 + t;
    if (v < VOCAB) {
      const f32x4* src = reinterpret_cast<const f32x4*>(emb + (size_t)v * D_MODEL + dblk * 32);
      #pragma unroll
      for (int i = 0; i < 8; ++i) {
        f32x4 a = src[i];
        #pragma unroll
        for (int j = 0; j < 4; ++j) tileS[t][i * 4 + j] = f2bf(a[j]);
      }
    } else {
      #pragma unroll
      for (int i = 0; i < 32; ++i) tileS[t][i] = 0;
    }
  }
  __syncthreads();
  #pragma unroll
  for (int i = 0; i < 4; ++i) {
    const int c = t + i * 256;
    const int l = c & 63;
    const int ks2 = c >> 6;
    const int dloc = l & 31;
    s16x8 o;
    #pragma unroll
    for (int j = 0; j < 8; ++j) o[j] = tileS[ks2 * 16 + (l >> 5) * 8 + j][dloc];
    const size_t cid = (size_t)tile * 32768 + (size_t)w * 4096 + (size_t)ks2 * 256
                     + (size_t)dt * 64 + l;
    reinterpret_cast<s16x8*>(ep)[cid] = o;
  }
}

__global__ __launch_bounds__(256) void k_pack_bias(const float* __restrict__ b,
                                                   unsigned short* __restrict__ bp) {
  const int v = blockIdx.x * 256 + threadIdx.x;
  bp[v] = f2bf(v < VOCAB ? b[v] : 0.f);
}

__global__ __launch_bounds__(512, 2)
void k_main(const float* __restrict__ enc, const unsigned short* __restrict__ biasb,
            const unsigned short* __restrict__ Wp, const unsigned short* __restrict__ Ep,
            float* __restrict__ o_part, float* __restrict__ den_part) {
  __shared__ unsigned short Qf[65536];
  __shared__ unsigned short Pl[16384];

  const int bx = blockIdx.x;
  const int xcd = bx & 7;
  const int vs = xcd & 3;
  const int rb = (xcd >> 2) * 32 + (bx >> 3);
  const int row0 = rb * RB;
  const int tid = threadIdx.x;
  const int w = tid >> 6;
  const int l = tid & 63;
  const int l31 = l & 31;
  const int lh = l >> 5;

  for (int c = tid; c < RB * 128; c += 512) {
    const int qq = c >> 7;
    const int kc = c & 127;
    const f32x4* src = reinterpret_cast<const f32x4*>(enc + (size_t)(row0 + qq) * D_MODEL + kc * 8);
    f32x4 a = src[0], b = src[1];
    s16x8 o;
    o[0]=f2bf(a[0]); o[1]=f2bf(a[1]); o[2]=f2bf(a[2]); o[3]=f2bf(a[3]);
    o[4]=f2bf(b[0]); o[5]=f2bf(b[1]); o[6]=f2bf(b[2]); o[7]=f2bf(b[3]);
    const int qtt = qq >> 5, ks = kc >> 1, lane = ((kc & 1) << 5) | (qq & 31);
    reinterpret_cast<s16x8*>(Qf)[(qtt * 64 + ks) * 64 + lane] = o;
  }
  __syncthreads();

  const s16x8* Qv = reinterpret_cast<const s16x8*>(Qf);
  char* PlB = reinterpret_cast<char*>(Pl);
  const uint32_t swz = (uint32_t)(l31 & 15) << 4;

  float den0 = 0.f, den1 = 0.f;
  f32x16 Oacc[4][2];
  #pragma unroll
  for (int dt = 0; dt < 4; ++dt)
    #pragma unroll
    for (int qt = 0; qt < 2; ++qt)
      #pragma unroll
      for (int i = 0; i < 16; ++i) Oacc[dt][qt][i] = 0.f;

  for (int it = 0; it < ITERS; ++it) {
    const int tile = vs * ITERS + it;
    const unsigned short* bb = biasb + tile * 256 + w * 32 + 4 * lh;
    const s16x4 b0 = *reinterpret_cast<const s16x4*>(bb);
    const s16x4 b1 = *reinterpret_cast<const s16x4*>(bb + 8);
    const s16x4 b2 = *reinterpret_cast<const s16x4*>(bb + 16);
    const s16x4 b3 = *reinterpret_cast<const s16x4*>(bb + 24);

    f32x16 S0, S1;
    #pragma unroll
    for (int i = 0; i < 16; ++i) { S0[i] = 0.f; S1[i] = 0.f; }
    const s16x8* wv = reinterpret_cast<const s16x8*>(Wp) + (size_t)tile * 32768 + w * 4096 + l;
    #pragma unroll 4
    for (int ks = 0; ks < 64; ++ks) {
      const s16x8 wf = wv[(size_t)ks * 64];
      const s16x8 q0 = Qv[(size_t)(0 * 64 + ks) * 64 + l];
      const s16x8 q1 = Qv[(size_t)(1 * 64 + ks) * 64 + l];
      S0 = __builtin_amdgcn_mfma_f32_32x32x16_bf16(wf, q0, S0, 0, 0, 0);
      S1 = __builtin_amdgcn_mfma_f32_32x32x16_bf16(wf, q1, S1, 0, 0, 0);
    }
    __syncthreads();

    const s16x8* ev = reinterpret_cast<const s16x8*>(Ep) + (size_t)tile * 32768 + w * 4096 + l;
    {
      const int vbase = tile * 256 + w * 32 + 4 * lh;
      const uint32_t vb2base = (uint32_t)(w * 32 + 4 * lh) * 2u;
      #pragma unroll
      for (int m = 0; m < 4; ++m) {
        const s16x4 bm = (m == 0) ? b0 : (m == 1) ? b1 : (m == 2) ? b2 : b3;
        s16x4 pk0, pk1;
        #pragma unroll
        for (int r = 0; r < 4; ++r) {
          const float bvr = bf2f((unsigned short)bm[r]);
          float e0 = __expf(S0[4 * m + r] + bvr);
          float e1 = __expf(S1[4 * m + r] + bvr);
          if (vbase + 8 * m + r >= VOCAB) { e0 = 0.f; e1 = 0.f; }
          den0 += e0; den1 += e1;
          pk0[r] = f2bf(e0); pk1[r] = f2bf(e1);
        }
        const uint32_t vb2 = vb2base + (uint32_t)(8 * m) * 2u;
        *reinterpret_cast<s16x4*>(PlB + (uint32_t)l31 * 512u + (vb2 ^ swz)) = pk0;
        *reinterpret_cast<s16x4*>(PlB + (uint32_t)(32 + l31) * 512u + (vb2 ^ swz)) = pk1;
      }
    }
    __syncthreads();

    #pragma unroll 4
    for (int ks2 = 0; ks2 < 16; ++ks2) {
      const uint32_t voff = (uint32_t)(ks2 * 32 + lh * 16);
      const s16x8 p0 = *reinterpret_cast<const s16x8*>(PlB + (uint32_t)l31 * 512u + (voff ^ swz));
      const s16x8 p1 = *reinterpret_cast<const s16x8*>(PlB + (uint32_t)(32 + l31) * 512u + (voff ^ swz));
      #pragma unroll
      for (int dt = 0; dt < 4; ++dt) {
        const s16x8 ef = ev[(size_t)ks2 * 256 + dt * 64];
        Oacc[dt][0] = __builtin_amdgcn_mfma_f32_32x32x16_bf16(ef, p0, Oacc[dt][0], 0, 0, 0);
        Oacc[dt][1] = __builtin_amdgcn_mfma_f32_32x32x16_bf16(ef, p1, Oacc[dt][1], 0, 0, 0);
      }
    }
  }

  float* ob = o_part + ((size_t)vs * ROWS + row0) * D_MODEL;
  #pragma unroll
  for (int qt = 0; qt < 2; ++qt) {
    #pragma unroll
    for (int dt = 0; dt < 4; ++dt) {
      const f32x16& A = Oacc[dt][qt];
      const size_t rowoff = (size_t)(qt * 32 + l31) * D_MODEL;
      const int dbase = (dt * 8 + w) * 32 + 4 * lh;
      #pragma unroll
      for (int m = 0; m < 4; ++m) {
        f32x4 v4 = { A[4 * m], A[4 * m + 1], A[4 * m + 2], A[4 * m + 3] };
        *reinterpret_cast<f32x4*>(ob + rowoff + dbase + 8 * m) = v4;
      }
    }
  }

  __syncthreads();
  den0 += __shfl_xor(den0, 32);
  den1 += __shfl_xor(den1, 32);
  float* red = reinterpret_cast<float*>(Pl);
  if (l < 32) {
    red[(w * 2 + 0) * 32 + l31] = den0;
    red[(w * 2 + 1) * 32 + l31] = den1;
  }
  __syncthreads();
  if (tid < 64) {
    const int qtt = tid >> 5, col = tid & 31;
    float s = 0.f;
    #pragma unroll
    for (int s2 = 0; s2 < 8; ++s2) s += red[(s2 * 2 + qtt) * 32 + col];
    den_part[(size_t)vs * ROWS + row0 + tid] = s;
  }
}

__global__ __launch_bounds__(256)
void k_ln(const float* __restrict__ enc, const float* __restrict__ o_part,
          const float* __restrict__ den_part, const float* __restrict__ gam,
          const float* __restrict__ bet, float* __restrict__ out) {
  __shared__ float r1[4], r2[4];
  const int row = blockIdx.x;
  const int t = threadIdx.x;
  const int d = t * 4;
  float den = 0.f;
  #pragma unroll
  for (int p = 0; p < VS; ++p) den += den_part[(size_t)p * ROWS + row];
  const float inv = 1.f / den;
  f32x4 acc = {0.f, 0.f, 0.f, 0.f};
  #pragma unroll
  for (int p = 0; p < VS; ++p) {
    const f32x4 a = *reinterpret_cast<const f32x4*>(o_part + ((size_t)p * ROWS + row) * D_MODEL + d);
    #pragma unroll
    for (int jj = 0; jj < 4; ++jj) acc[jj] += a[jj];
  }
  const f32x4 e = *reinterpret_cast<const f32x4*>(enc + (size_t)row * D_MODEL + d);
  f32x4 y;
  #pragma unroll
  for (int jj = 0; jj < 4; ++jj) y[jj] = e[jj] + acc[jj] * inv;
  float s1 = y[0] + y[1] + y[2] + y[3];
  float s2 = y[0]*y[0] + y[1]*y[1] + y[2]*y[2] + y[3]*y[3];
  #pragma unroll
  for (int off = 1; off < 64; off <<= 1) {
    s1 += __shfl_xor(s1, off);
    s2 += __shfl_xor(s2, off);
  }
  if ((t & 63) == 0) { r1[t >> 6] = s1; r2[t >> 6] = s2; }
  __syncthreads();
  const float S1 = r1[0] + r1[1] + r1[2] + r1[3];
  const float S2 = r2[0] + r2[1] + r2[2] + r2[3];
  const float mean = S1 * (1.f / D_MODEL);
  const float var = S2 * (1.f / D_MODEL) - mean * mean;
  const float rs = rsqrtf(var + LN_EPS);
  const f32x4 gv = *reinterpret_cast<const f32x4*>(gam + d);
  const f32x4 bv = *reinterpret_cast<const f32x4*>(bet + d);
  f32x4 o;
  #pragma unroll
  for (int jj = 0; jj < 4; ++jj) o[jj] = (y[jj] - mean) * rs * gv[jj] + bv[jj];
  *reinterpret_cast<f32x4*>(out + (size_t)row * D_MODEL + d) = o;
}

// ============================================================================
extern "C" void kernel_launch(void* const* d_in, const int* in_sizes, int n_in,
                              void* d_out, int out_size, void* d_ws, size_t ws_size,
                              hipStream_t stream) {
  const float* enc = (const float*)d_in[0];
  const float* pw  = (const float*)d_in[1];
  const float* pb  = (const float*)d_in[2];
  const float* emb = (const float*)d_in[3];
  const float* gam = (const float*)d_in[4];
  const float* bet = (const float*)d_in[5];
  float* out = (float*)d_out;

  // ---- new-path workspace layout ----
  size_t off = 0;
  unsigned short* encb = (unsigned short*)((char*)d_ws + off); off += (size_t)ROWS * D_MODEL * 2;
  unsigned short* Wb   = (unsigned short*)((char*)d_ws + off); off += (size_t)VP * D_MODEL * 2;
  unsigned short* ET   = (unsigned short*)((char*)d_ws + off); off += (size_t)D_MODEL * VP * 2;
  unsigned short* P    = (unsigned short*)((char*)d_ws + off); off += (size_t)ROWS * VP * 2;
  float* opart         = (float*)((char*)d_ws + off);          off += (size_t)8 * ROWS * D_MODEL * 4;
  float* den           = (float*)((char*)d_ws + off);          off += (size_t)ROWS * 8 * 4;
  const size_t NEED_NEW = off;

  if (ws_size >= NEED_NEW) {
    hipMemsetAsync(den, 0, (size_t)ROWS * 8 * 4, stream);
    k_cast_enc<<<(ROWS * D_MODEL / 8) / 256, 256, 0, stream>>>(enc, encb);
    k_pack_wlin<<<((size_t)VP * D_MODEL / 8) / 256, 256, 0, stream>>>(pw, Wb);
    k_pack_et<<<dim3(VP / 32, D_MODEL / 32), dim3(32, 8), 0, stream>>>(emb, ET);
    k_gemm1<<<6400, 512, 0, stream>>>(encb, Wb, pb, P, den);
    k_gemm2<<<1024, 512, 0, stream>>>(P, ET, opart);
    k_ln2<<<ROWS, 256, 0, stream>>>(enc, opart, den, gam, bet, out);
    return;
  }

  // ---- fallback (R3) workspace layout ----
  off = 0;
  unsigned short* Wp = (unsigned short*)((char*)d_ws + off); off += (size_t)NTILES * 32768 * 16;
  unsigned short* Ep = (unsigned short*)((char*)d_ws + off); off += (size_t)NTILES * 32768 * 16;
  unsigned short* biasb = (unsigned short*)((char*)d_ws + off); off += (size_t)VP * 2;
  float* o_part = (float*)((char*)d_ws + off); off += (size_t)VS * ROWS * D_MODEL * 4;
  float* den_part = (float*)((char*)d_ws + off); off += (size_t)VS * ROWS * 4;

  if (off > ws_size) {
    hipMemsetAsync(d_out, 0x7f, (size_t)out_size * 4, stream);
    return;
  }

  k_pack_w<<<NTILES * 32768 / 256, 256, 0, stream>>>(pw, Wp);
  k_pack_e<<<dim3(NTILES, 32), 256, 0, stream>>>(emb, Ep);
  k_pack_bias<<<VP / 256, 256, 0, stream>>>(pb, biasb);
  k_main<<<256, 512, 0, stream>>>(enc, biasb, Wp, Ep, o_part, den_part);
  k_ln<<<ROWS, 256, 0, stream>>>(enc, o_part, den_part, gam, bet, out);
}